// Round 1
// baseline (442.840 us; speedup 1.0000x reference)
//
#include <hip/hip_runtime.h>
#include <cstddef>
#include <cstdint>

// Problem constants: x (32,64,64,16) f32; W (16,16,448,448) f32; bias (16,16) f32.
// Kept bands per axis after truncation: {cA6, cD6, cD5, cD1} -> full-layout band ids {0,1,2,6}.
// Layouts:
//   X1 / Z1 : (a, u in [0,256), j in [0,64), ch in [0,16))   -- 8,388,608 floats (32 MB)
//   T       : (ac, u in [0,256), v in [0,256), ch in [0,16)) -- na*1,048,576 floats

#define X1_IDX(a,u,j,d) ((((size_t)(a)*256 + (u))*64 + (j))*16 + (d))

// ---------------- K1: SWT along axis 1 (i -> u bands), x -> X1 ----------------
// block 64 = 16 d x 4 j ; grid (32 a, 16 jc)
__global__ __launch_bounds__(64) void k_swt1(const float* __restrict__ x,
                                             float* __restrict__ X1) {
  const int tid = threadIdx.x;
  const int d = tid & 15, jl = tid >> 4;
  const int a = blockIdx.x;
  const int j = blockIdx.y * 4 + jl;
  __shared__ float col[64 * 64];  // [i][tid]
  const float* xp = x + ((size_t)a * 4096 + j) * 16 + d;  // + i*1024
  float S = 0.f;
  for (int i = 0; i < 64; ++i) {
    float v = xp[(size_t)i * 1024];
    col[i * 64 + tid] = v;
    S += v;
  }
  const float cA = S * 0.015625f;  // mean (cA6, constant along axis)
  float w4 = 0.f, w4b = 0.f;
  for (int t = 0; t < 16; ++t)  w4  += col[t * 64 + tid];
  for (int t = 16; t < 32; ++t) w4b += col[t * 64 + tid];
  float w5 = w4 + w4b;
  float* X1p = X1 + X1_IDX(a, 0, j, d);  // stride per u = 1024
  for (int u = 0; u < 64; ++u) {
    const float c0 = col[u * 64 + tid];
    const float c16 = col[((u + 16) & 63) * 64 + tid];
    const float c32 = col[((u + 32) & 63) * 64 + tid];
    const float c1 = col[((u + 1) & 63) * 64 + tid];
    X1p[(size_t)(u) * 1024]        = cA;                              // cA6
    X1p[(size_t)(64 + u) * 1024]   = w5 * 0.03125f - cA;              // cD6 = a5[u]-cA
    X1p[(size_t)(128 + u) * 1024]  = (w4 - w4b) * 0.03125f;           // cD5 = (a4[u]-a4[u+16])/2
    X1p[(size_t)(192 + u) * 1024]  = (c0 - c1) * 0.5f;                // cD1
    w4 += c16 - c0;
    w4b += c32 - c16;
    w5 += c32 - c0;
  }
}

// ---------------- K2: SWT along axis 2 (j -> v bands), X1 -> T (batch chunk) ----------------
// block 64 = 16 d x 4 u ; grid (na, 64 uc)
__global__ __launch_bounds__(64) void k_swt2(const float* __restrict__ X1,
                                             float* __restrict__ T, int a0) {
  const int tid = threadIdx.x;
  const int d = tid & 15, ul = tid >> 4;
  const int ac = blockIdx.x, a = a0 + ac;
  const int u = blockIdx.y * 4 + ul;
  __shared__ float col[64 * 64];
  const float* xp = X1 + X1_IDX(a, u, 0, d);  // + j*16
  float S = 0.f;
  for (int i = 0; i < 64; ++i) {
    float v = xp[i * 16];
    col[i * 64 + tid] = v;
    S += v;
  }
  const float cA = S * 0.015625f;
  float w4 = 0.f, w4b = 0.f;
  for (int t = 0; t < 16; ++t)  w4  += col[t * 64 + tid];
  for (int t = 16; t < 32; ++t) w4b += col[t * 64 + tid];
  float w5 = w4 + w4b;
  float* Tp = T + (((size_t)ac * 256 + u) * 256) * 16 + d;  // stride per v = 16
  for (int v = 0; v < 64; ++v) {
    const float c0 = col[v * 64 + tid];
    const float c16 = col[((v + 16) & 63) * 64 + tid];
    const float c32 = col[((v + 32) & 63) * 64 + tid];
    const float c1 = col[((v + 1) & 63) * 64 + tid];
    Tp[(size_t)(v) * 16]        = cA;
    Tp[(size_t)(64 + v) * 16]   = w5 * 0.03125f - cA;
    Tp[(size_t)(128 + v) * 16]  = (w4 - w4b) * 0.03125f;
    Tp[(size_t)(192 + v) * 16]  = (c0 - c1) * 0.5f;
    w4 += c16 - c0;
    w4b += c32 - c16;
    w5 += c32 - c0;
  }
}

// ---------------- K3: per-location channel mix, in place on T ----------------
// y[a,u,v,e] = sum_d T[a,u,v,d] * W[d,e,B(u),C(v)]
// block 256 ; grid (256 u, 16 vchunks of 16)
__global__ __launch_bounds__(256) void k_mix(float* __restrict__ T,
                                             const float* __restrict__ W, int na) {
  const int t = threadIdx.x;
  const int u = blockIdx.x;
  const int vc = blockIdx.y;
  const int kb = vc >> 2;
  const int v0 = vc * 16;
  const int ub = u >> 6;
  const int Brow = (ub == 3 ? 6 : ub) * 64 + (u & 63);
  const int Ccol = (kb == 3 ? 6 : kb) * 64 + (vc & 3) * 16;
  __shared__ float Wl[16 * 256];      // [vl][(d*16+e)]
  __shared__ float Tl[32 * 16 * 17];  // [a][vl][d] padded to 17
  {
    // thread t owns (d,e) = t ; 16 consecutive C values
    const float* wp = W + (size_t)t * 200704 + (size_t)Brow * 448 + Ccol;
    #pragma unroll
    for (int i = 0; i < 16; i += 4) {
      float4 w4v = *(const float4*)(wp + i);
      Wl[(i + 0) * 256 + t] = w4v.x;
      Wl[(i + 1) * 256 + t] = w4v.y;
      Wl[(i + 2) * 256 + t] = w4v.z;
      Wl[(i + 3) * 256 + t] = w4v.w;
    }
  }
  for (int idx = t; idx < na * 256; idx += 256) {
    int a = idx >> 8, rem = idx & 255, vl = rem >> 4, dd = rem & 15;
    Tl[(a * 16 + vl) * 17 + dd] =
        T[(((size_t)a * 256 + u) * 256 + v0 + vl) * 16 + dd];
  }
  __syncthreads();
  const int e = t & 15, al = t >> 4;
  float y[2][16];
  for (int aa = 0; aa < na; aa += 16) {
    int a = aa + al;
    if (a < na) {
      for (int vl = 0; vl < 16; ++vl) {
        float acc = 0.f;
        #pragma unroll
        for (int dd = 0; dd < 16; ++dd)
          acc += Tl[(a * 16 + vl) * 17 + dd] * Wl[vl * 256 + dd * 16 + e];
        y[aa >> 4][vl] = acc;
      }
    }
  }
  __syncthreads();
  for (int aa = 0; aa < na; aa += 16) {
    int a = aa + al;
    if (a < na)
      for (int vl = 0; vl < 16; ++vl)
        T[(((size_t)a * 256 + u) * 256 + v0 + vl) * 16 + e] = y[aa >> 4][vl];
  }
}

// ---------------- K4: inverse SWT along axis 2 (v bands -> j), T -> Z1 ----------------
// block 64 = 16 e x 4 u ; grid (na, 64 uc)
__global__ __launch_bounds__(64) void k_iswt2(const float* __restrict__ T,
                                              float* __restrict__ Z1, int a0) {
  const int tid = threadIdx.x, e = tid & 15, ul = tid >> 4;
  const int ac = blockIdx.x, a = a0 + ac;
  const int u = blockIdx.y * 4 + ul;
  __shared__ float A[64 * 64], Bv[64 * 64];
  const float* Tp = T + (((size_t)ac * 256 + u) * 256) * 16 + e;
  for (int i = 0; i < 64; ++i) A[i * 64 + tid] = Tp[(size_t)i * 16];  // a6 = cA6
  for (int i = 0; i < 64; ++i) {  // level 6, s=32, cD6 = band 1
    float D = Tp[(size_t)(64 + i) * 16];
    float D2 = Tp[(size_t)(64 + ((i - 32) & 63)) * 16];
    Bv[i * 64 + tid] = 0.5f * (A[i * 64 + tid] + D + A[((i - 32) & 63) * 64 + tid] - D2);
  }
  for (int i = 0; i < 64; ++i) {  // level 5, s=16, cD5 = band 2
    float D = Tp[(size_t)(128 + i) * 16];
    float D2 = Tp[(size_t)(128 + ((i - 16) & 63)) * 16];
    A[i * 64 + tid] = 0.5f * (Bv[i * 64 + tid] + D + Bv[((i - 16) & 63) * 64 + tid] - D2);
  }
  for (int i = 0; i < 64; ++i)  // level 4, s=8, cD=0
    Bv[i * 64 + tid] = 0.5f * (A[i * 64 + tid] + A[((i - 8) & 63) * 64 + tid]);
  for (int i = 0; i < 64; ++i)  // level 3, s=4
    A[i * 64 + tid] = 0.5f * (Bv[i * 64 + tid] + Bv[((i - 4) & 63) * 64 + tid]);
  for (int i = 0; i < 64; ++i)  // level 2, s=2
    Bv[i * 64 + tid] = 0.5f * (A[i * 64 + tid] + A[((i - 2) & 63) * 64 + tid]);
  float* Zp = Z1 + X1_IDX(a, u, 0, e);
  for (int i = 0; i < 64; ++i) {  // level 1, s=1, cD1 = band 3
    float D = Tp[(size_t)(192 + i) * 16];
    float D2 = Tp[(size_t)(192 + ((i - 1) & 63)) * 16];
    Zp[(size_t)i * 16] =
        0.5f * (Bv[i * 64 + tid] + D + Bv[((i - 1) & 63) * 64 + tid] - D2);
  }
}

// ---------------- K5: inverse SWT along axis 1 (u bands -> i) + bias skip -> out ----------------
// block 64 = 16 e x 4 j ; grid (32 a, 16 jc)
__global__ __launch_bounds__(64) void k_iswt1(const float* __restrict__ Z1,
                                              const float* __restrict__ x,
                                              const float* __restrict__ bias,
                                              float* __restrict__ out) {
  const int tid = threadIdx.x, e = tid & 15, jl = tid >> 4;
  const int a = blockIdx.x, j = blockIdx.y * 4 + jl;
  __shared__ float A[64 * 64], Bv[64 * 64];
  __shared__ float bs[256];
  for (int i = tid; i < 256; i += 64) bs[i] = bias[i];
  __syncthreads();
  const float* Zp = Z1 + (size_t)a * 262144 + (size_t)j * 16 + e;  // + u*1024
  for (int i = 0; i < 64; ++i) A[i * 64 + tid] = Zp[(size_t)i * 1024];
  for (int i = 0; i < 64; ++i) {
    float D = Zp[(size_t)(64 + i) * 1024];
    float D2 = Zp[(size_t)(64 + ((i - 32) & 63)) * 1024];
    Bv[i * 64 + tid] = 0.5f * (A[i * 64 + tid] + D + A[((i - 32) & 63) * 64 + tid] - D2);
  }
  for (int i = 0; i < 64; ++i) {
    float D = Zp[(size_t)(128 + i) * 1024];
    float D2 = Zp[(size_t)(128 + ((i - 16) & 63)) * 1024];
    A[i * 64 + tid] = 0.5f * (Bv[i * 64 + tid] + D + Bv[((i - 16) & 63) * 64 + tid] - D2);
  }
  for (int i = 0; i < 64; ++i)
    Bv[i * 64 + tid] = 0.5f * (A[i * 64 + tid] + A[((i - 8) & 63) * 64 + tid]);
  for (int i = 0; i < 64; ++i)
    A[i * 64 + tid] = 0.5f * (Bv[i * 64 + tid] + Bv[((i - 4) & 63) * 64 + tid]);
  for (int i = 0; i < 64; ++i)
    Bv[i * 64 + tid] = 0.5f * (A[i * 64 + tid] + A[((i - 2) & 63) * 64 + tid]);
  const float* xp = x + ((size_t)a * 4096 + j) * 16;  // + i*1024 + d
  float* op = out + ((size_t)a * 4096 + j) * 16 + e;  // + i*1024
  for (int i = 0; i < 64; ++i) {
    float D = Zp[(size_t)(192 + i) * 1024];
    float D2 = Zp[(size_t)(192 + ((i - 1) & 63)) * 1024];
    float r = 0.5f * (Bv[i * 64 + tid] + D + Bv[((i - 1) & 63) * 64 + tid] - D2);
    float s = 0.f;
    #pragma unroll
    for (int dd = 0; dd < 16; ++dd) s += xp[(size_t)i * 1024 + dd] * bs[e * 16 + dd];
    op[(size_t)i * 1024] = r + s;
  }
}

extern "C" void kernel_launch(void* const* d_in, const int* in_sizes, int n_in,
                              void* d_out, int out_size, void* d_ws, size_t ws_size,
                              hipStream_t stream) {
  const float* x = (const float*)d_in[0];
  const float* W = (const float*)d_in[1];
  const float* bias = (const float*)d_in[2];
  float* out = (float*)d_out;
  float* X1 = (float*)d_ws;            // 8,388,608 floats (also reused as Z1)
  float* T = X1 + 8388608;             // na * 1,048,576 floats
  // Pick largest batch chunk that fits the workspace.
  int na = 32;
  while (na > 1 && ((size_t)8388608 + (size_t)na * 1048576) * 4 > ws_size) na >>= 1;

  k_swt1<<<dim3(32, 16), 64, 0, stream>>>(x, X1);
  for (int a0 = 0; a0 < 32; a0 += na) {
    k_swt2<<<dim3(na, 64), 64, 0, stream>>>(X1, T, a0);
    k_mix<<<dim3(256, 16), 256, 0, stream>>>(T, W, na);
    k_iswt2<<<dim3(na, 64), 64, 0, stream>>>(T, X1, a0);  // Z1 overwrites X1 region (per-batch safe)
  }
  k_iswt1<<<dim3(32, 16), 64, 0, stream>>>(X1, x, bias, out);
}

// Round 4
// 401.713 us; speedup vs baseline: 1.1024x; 1.1024x over previous
//
#include <hip/hip_runtime.h>
#include <cstddef>
#include <cstdint>

// x (32,64,64,16) f32; W (16,16,448,448) f32; bias (16,16) f32.
// Kept bands per axis: {cA6, cD6, cD5, cD1} -> full-layout band blocks {0,1,2,6}.
// X1 (reused in place as Z1): (a, u in [0,256), j in [0,64), ch 16) = 32 MB in d_ws.

#define X1_IDX(a,u,j,d) ((((size_t)(a)*256 + (u))*64 + (j))*16 + (d))

// ---------------- K1: SWT along axis 1 (i -> u bands), x -> X1 ----------------
__global__ __launch_bounds__(64) void k_swt1(const float* __restrict__ x,
                                             float* __restrict__ X1) {
  const int tid = threadIdx.x;
  const int d = tid & 15, jl = tid >> 4;
  const int a = blockIdx.x;
  const int j = blockIdx.y * 4 + jl;
  __shared__ float col[64 * 64];  // [i][tid]
  const float* xp = x + ((size_t)a * 4096 + j) * 16 + d;  // + i*1024
  float S = 0.f;
  for (int i = 0; i < 64; ++i) {
    float v = xp[(size_t)i * 1024];
    col[i * 64 + tid] = v;
    S += v;
  }
  const float cA = S * 0.015625f;
  float w4 = 0.f, w4b = 0.f;
  for (int t = 0; t < 16; ++t)  w4  += col[t * 64 + tid];
  for (int t = 16; t < 32; ++t) w4b += col[t * 64 + tid];
  float w5 = w4 + w4b;
  float* X1p = X1 + X1_IDX(a, 0, j, d);  // stride per u = 1024
  for (int u = 0; u < 64; ++u) {
    const float c0 = col[u * 64 + tid];
    const float c16 = col[((u + 16) & 63) * 64 + tid];
    const float c32 = col[((u + 32) & 63) * 64 + tid];
    const float c1 = col[((u + 1) & 63) * 64 + tid];
    X1p[(size_t)(u) * 1024]        = cA;
    X1p[(size_t)(64 + u) * 1024]   = w5 * 0.03125f - cA;
    X1p[(size_t)(128 + u) * 1024]  = (w4 - w4b) * 0.03125f;
    X1p[(size_t)(192 + u) * 1024]  = (c0 - c1) * 0.5f;
    w4 += c16 - c0;
    w4b += c32 - c16;
    w5 += c32 - c0;
  }
}

// ---------------- Fused K2+K3+K4: axis-2 SWT -> channel mix -> axis-2 iSWT ----------------
// Grid: (ac = 4, u = 256), block 256. In-place on X1 (each block owns disjoint
// X1[a0..a0+7][u][:][:] slices). LDS: Ts bands [a][v][d] skewed + W panel chunk.
#define APB 8
#define TS_STRIDE 4104  // 256*16 + 8 skew -> a-groups land on different banks
#define TS(a,v,d) ((a) * TS_STRIDE + (v) * 16 + (d))
#define WL_STRIDE 264   // 256 + 8 skew

__global__ __launch_bounds__(256, 1) void k_fused(float* __restrict__ X1,
                                                  const float* __restrict__ W) {
  const int t = threadIdx.x;
  const int a0 = blockIdx.x * APB;
  const int u = blockIdx.y;
  const int ub = u >> 6;
  const int Brow = (ub == 3 ? 6 : ub) * 64 + (u & 63);
  __shared__ float Ts[APB * TS_STRIDE];   // 131,328 B
  __shared__ float Wl[16 * WL_STRIDE];    //  16,896 B  (total 144.8 KiB)

  // ---- Phase A: load column from global into regs, write bands to Ts ----
  if (t < 128) {
    const int a = t >> 4, d = t & 15;
    const float* xp = X1 + X1_IDX(a0 + a, u, 0, d);  // stride per j = 16
    float raw[64];
    float S = 0.f, w4 = 0.f, w4b = 0.f;
#pragma unroll
    for (int j = 0; j < 64; ++j) {
      raw[j] = xp[j * 16];
      S += raw[j];
    }
#pragma unroll
    for (int j = 0; j < 16; ++j) w4 += raw[j];
#pragma unroll
    for (int j = 16; j < 32; ++j) w4b += raw[j];
    const float cA = S * 0.015625f;
    float w5 = w4 + w4b;
#pragma unroll
    for (int v = 0; v < 64; ++v) {
      Ts[TS(a, v, d)]       = cA;                                    // cA6
      Ts[TS(a, 64 + v, d)]  = w5 * 0.03125f - cA;                    // cD6
      Ts[TS(a, 128 + v, d)] = (w4 - w4b) * 0.03125f;                 // cD5
      Ts[TS(a, 192 + v, d)] = (raw[v] - raw[(v + 1) & 63]) * 0.5f;   // cD1
      const float c0 = raw[v], c16 = raw[(v + 16) & 63], c32 = raw[(v + 32) & 63];
      w4 += c16 - c0;
      w4b += c32 - c16;
      w5 += c32 - c0;
    }
  }
  __syncthreads();

  // ---- Phase B: per-location channel mix, in place on Ts ----
  // y[a,v,e] = sum_d Ts[a,v,d] * W[d,e,Brow,C(v)]
  const int vl = t >> 4, e = t & 15;
  const float* wbase = W + (size_t)t * 200704 + (size_t)Brow * 448;  // t == (d,e)
  for (int vg = 0; vg < 16; ++vg) {
    const int kb = vg >> 2;
    const int Ccol = (kb == 3 ? 6 : kb) * 64 + (vg & 3) * 16;
    __syncthreads();  // prior vg done reading Wl
    {
      const float* wp = wbase + Ccol;
#pragma unroll
      for (int i = 0; i < 16; i += 4) {
        float4 wv = *(const float4*)(wp + i);
        Wl[(i + 0) * WL_STRIDE + t] = wv.x;
        Wl[(i + 1) * WL_STRIDE + t] = wv.y;
        Wl[(i + 2) * WL_STRIDE + t] = wv.z;
        Wl[(i + 3) * WL_STRIDE + t] = wv.w;
      }
    }
    __syncthreads();
    const int v = vg * 16 + vl;
    float wreg[16];
#pragma unroll
    for (int d = 0; d < 16; ++d) wreg[d] = Wl[vl * WL_STRIDE + d * 16 + e];
#pragma unroll
    for (int a = 0; a < APB; ++a) {
      const float4 t0 = *(const float4*)&Ts[TS(a, v, 0)];
      const float4 t1 = *(const float4*)&Ts[TS(a, v, 4)];
      const float4 t2 = *(const float4*)&Ts[TS(a, v, 8)];
      const float4 t3 = *(const float4*)&Ts[TS(a, v, 12)];
      float acc = t0.x * wreg[0] + t0.y * wreg[1] + t0.z * wreg[2] + t0.w * wreg[3]
                + t1.x * wreg[4] + t1.y * wreg[5] + t1.z * wreg[6] + t1.w * wreg[7]
                + t2.x * wreg[8] + t2.y * wreg[9] + t2.z * wreg[10] + t2.w * wreg[11]
                + t3.x * wreg[12] + t3.y * wreg[13] + t3.z * wreg[14] + t3.w * wreg[15];
      // all same-v readers are in this wave; DS ops are in-order -> safe in-place
      Ts[TS(a, v, e)] = acc;
    }
  }
  __syncthreads();

  // ---- Phase C: axis-2 iSWT in registers, write back to X1 (as Z1) ----
  if (t < 128) {
    const int a = t >> 4, ee = t & 15;
    const float cA = Ts[TS(a, 0, ee)];
    float d6[64];
#pragma unroll
    for (int i = 0; i < 64; ++i) d6[i] = Ts[TS(a, 64 + i, ee)];
    float b6[64];
#pragma unroll
    for (int i = 0; i < 64; ++i) b6[i] = cA + 0.5f * (d6[i] - d6[(i - 32) & 63]);
    float d5[64];
#pragma unroll
    for (int i = 0; i < 64; ++i) d5[i] = Ts[TS(a, 128 + i, ee)];
    float a5[64];
#pragma unroll
    for (int i = 0; i < 64; ++i)
      a5[i] = 0.5f * (b6[i] + d5[i] + b6[(i - 16) & 63] - d5[(i - 16) & 63]);
    float b4[64];
#pragma unroll
    for (int i = 0; i < 64; ++i) b4[i] = 0.5f * (a5[i] + a5[(i - 8) & 63]);
    float a3[64];
#pragma unroll
    for (int i = 0; i < 64; ++i) a3[i] = 0.5f * (b4[i] + b4[(i - 4) & 63]);
    float b2[64];
#pragma unroll
    for (int i = 0; i < 64; ++i) b2[i] = 0.5f * (a3[i] + a3[(i - 2) & 63]);
    float d1[64];
#pragma unroll
    for (int i = 0; i < 64; ++i) d1[i] = Ts[TS(a, 192 + i, ee)];
    float* zp = X1 + X1_IDX(a0 + a, u, 0, ee);  // stride per j = 16
#pragma unroll
    for (int j = 0; j < 64; ++j)
      zp[j * 16] = 0.5f * (b2[j] + d1[j] + b2[(j - 1) & 63] - d1[(j - 1) & 63]);
  }
}

// ---------------- K5: inverse SWT along axis 1 (u bands -> i) + bias skip -> out ----------------
__global__ __launch_bounds__(64) void k_iswt1(const float* __restrict__ Z1,
                                              const float* __restrict__ x,
                                              const float* __restrict__ bias,
                                              float* __restrict__ out) {
  const int tid = threadIdx.x, e = tid & 15, jl = tid >> 4;
  const int a = blockIdx.x, j = blockIdx.y * 4 + jl;
  __shared__ float A[64 * 64], Bv[64 * 64];
  __shared__ float bs[256];
  for (int i = tid; i < 256; i += 64) bs[i] = bias[i];
  __syncthreads();
  const float* Zp = Z1 + (size_t)a * 262144 + (size_t)j * 16 + e;  // + u*1024
  for (int i = 0; i < 64; ++i) A[i * 64 + tid] = Zp[(size_t)i * 1024];
  for (int i = 0; i < 64; ++i) {
    float D = Zp[(size_t)(64 + i) * 1024];
    float D2 = Zp[(size_t)(64 + ((i - 32) & 63)) * 1024];
    Bv[i * 64 + tid] = 0.5f * (A[i * 64 + tid] + D + A[((i - 32) & 63) * 64 + tid] - D2);
  }
  for (int i = 0; i < 64; ++i) {
    float D = Zp[(size_t)(128 + i) * 1024];
    float D2 = Zp[(size_t)(128 + ((i - 16) & 63)) * 1024];
    A[i * 64 + tid] = 0.5f * (Bv[i * 64 + tid] + D + Bv[((i - 16) & 63) * 64 + tid] - D2);
  }
  for (int i = 0; i < 64; ++i)
    Bv[i * 64 + tid] = 0.5f * (A[i * 64 + tid] + A[((i - 8) & 63) * 64 + tid]);
  for (int i = 0; i < 64; ++i)
    A[i * 64 + tid] = 0.5f * (Bv[i * 64 + tid] + Bv[((i - 4) & 63) * 64 + tid]);
  for (int i = 0; i < 64; ++i)
    Bv[i * 64 + tid] = 0.5f * (A[i * 64 + tid] + A[((i - 2) & 63) * 64 + tid]);
  const float* xp = x + ((size_t)a * 4096 + j) * 16;
  float* op = out + ((size_t)a * 4096 + j) * 16 + e;
  for (int i = 0; i < 64; ++i) {
    float D = Zp[(size_t)(192 + i) * 1024];
    float D2 = Zp[(size_t)(192 + ((i - 1) & 63)) * 1024];
    float r = 0.5f * (Bv[i * 64 + tid] + D + Bv[((i - 1) & 63) * 64 + tid] - D2);
    float s = 0.f;
#pragma unroll
    for (int dd = 0; dd < 16; ++dd) s += xp[(size_t)i * 1024 + dd] * bs[e * 16 + dd];
    op[(size_t)i * 1024] = r + s;
  }
}

extern "C" void kernel_launch(void* const* d_in, const int* in_sizes, int n_in,
                              void* d_out, int out_size, void* d_ws, size_t ws_size,
                              hipStream_t stream) {
  const float* x = (const float*)d_in[0];
  const float* W = (const float*)d_in[1];
  const float* bias = (const float*)d_in[2];
  float* out = (float*)d_out;
  float* X1 = (float*)d_ws;  // 32 MB; serves as both X1 and Z1 (in-place fused stage)

  k_swt1<<<dim3(32, 16), 64, 0, stream>>>(x, X1);
  k_fused<<<dim3(4, 256), 256, 0, stream>>>(X1, W);
  k_iswt1<<<dim3(32, 16), 64, 0, stream>>>(X1, x, bias, out);
}